// Round 11
// baseline (80.396 us; speedup 1.0000x reference)
//
#include <hip/hip_runtime.h>
#include <hip/hip_bf16.h>

typedef __bf16 bf16x8 __attribute__((ext_vector_type(8)));
typedef __bf16 bf16x4 __attribute__((ext_vector_type(4)));
typedef __bf16 bf16x2 __attribute__((ext_vector_type(2)));
typedef float f32x4 __attribute__((ext_vector_type(4)));
typedef float f32x16 __attribute__((ext_vector_type(16)));

#define S_LEN 2048
#define D_DIM 64
#define NQT   32

// pack two f32 -> u32 of 2 bf16 (compiler fuses to v_cvt_pk_bf16_f32)
static __device__ __forceinline__ unsigned pk2(float a, float b) {
  bf16x2 t; t[0] = (__bf16)a; t[1] = (__bf16)b;
  return __builtin_bit_cast(unsigned, t);
}

// ---------------- preprocess: 32x32-MFMA fragment images ----------------
// Per (bh, kt32) tile (32 k-rows), 4 KB each for K and Vt:
//  Kb chunk idx = t*64 + l (16B): K[kt*32 + (l&31)][t*16 + (l>>5)*8 + 0..7]
//  Vt chunk idx = (dt*2+ks)*64 + l: V[kt*32 + ks*16 + (l>>5)*8 + j][dt*32 + (l&31)]
__global__ __launch_bounds__(256) void preprocess_kernel(
    const float* __restrict__ Kg, const float* __restrict__ Vg,
    unsigned char* __restrict__ Kb, unsigned char* __restrict__ Vt) {
  __shared__ float buf[2048];   // 8 KB: one 32x64 fp32 tile
  const int tid  = threadIdx.x;
  const int tile = blockIdx.x;          // bh*64 + kt
  const float* kg = Kg + (long)tile * 2048;
  const float* vg = Vg + (long)tile * 2048;
  unsigned char* kb = Kb + (long)tile * 4096;
  unsigned char* vt = Vt + (long)tile * 4096;

  const int l = tid & 63, f = tid >> 6, h = l >> 5;

  // K: direct 16B-granular reads (L2 absorbs the striding; tiny kernel)
  {
    const float* kr = kg + (l & 31) * 64 + f * 16 + h * 8;
    float4 a = *reinterpret_cast<const float4*>(kr);
    float4 b = *reinterpret_cast<const float4*>(kr + 4);
    bf16x8 t;
    t[0]=(__bf16)a.x; t[1]=(__bf16)a.y; t[2]=(__bf16)a.z; t[3]=(__bf16)a.w;
    t[4]=(__bf16)b.x; t[5]=(__bf16)b.y; t[6]=(__bf16)b.z; t[7]=(__bf16)b.w;
    *reinterpret_cast<bf16x8*>(kb + tid * 16) = t;
  }
  // V: stage coalesced, gather rows (row-wise reads: conflict-free)
  #pragma unroll
  for (int i = 0; i < 2; ++i) {
    int idx = tid + 256 * i;   // 512 float4
    *reinterpret_cast<float4*>(buf + idx * 4) =
        *reinterpret_cast<const float4*>(vg + idx * 4);
  }
  __syncthreads();
  {
    int dt = f >> 1, ks = f & 1;
    int d  = dt * 32 + (l & 31);
    int k0 = ks * 16 + h * 8;
    bf16x8 t;
    #pragma unroll
    for (int j = 0; j < 8; ++j) t[j] = (__bf16)buf[(k0 + j) * 64 + d];
    *reinterpret_cast<bf16x8*>(vt + tid * 16) = t;
  }
}

// ---------------- main: 1-wave blocks, 32x32 MFMA, all-register softmax ----------------
// Wave owns 32 q-rows; KVBLK=32. Swapped QK^T (mfma(K,Q)) -> lane (qc,h) holds
// P[q=qc][k = crow(r,h)] with crow(r,h)=(r&3)+8*(r>>2)+4h. P->A-frag reshape
// done with __shfl_xor(32) + select (direction-unambiguous, unlike
// v_permlane32_swap operand order -- the round-10 bug). No LDS, no barriers.
__global__ __launch_bounds__(64) void attn_fwd_w32(
    const float* __restrict__ Qg, const unsigned char* __restrict__ Kb,
    const unsigned char* __restrict__ Vt, float* __restrict__ Og) {
  const int lane = threadIdx.x & 63;
  const int qc   = lane & 31;    // q column this lane tracks
  const int h    = lane >> 5;

  // decode: XCD-clustered bh (4 bh per XCD), longest q-groups first (LPT)
  const int lb = blockIdx.x;            // 0..2047
  const int e  = lb & 7;
  const int s  = lb >> 3;               // 0..255
  const int bh = e + 8 * (s >> 6);      // 4 bh per XCD
  const int qg = 63 - (s & 63);         // q-group of 32 rows, longest first
  const long base = (long)bh * (S_LEN * D_DIM);
  const int q0 = qg * 32;
  const int NT = qg + 1;                // # of 32-wide k-tiles

  // Q fragments (B-operand), prescaled by 1/8 * log2(e)
  bf16x8 qf[4];
  {
    const float qsc = 0.125f * 1.44269504f;
    const float* qp = Qg + base + (long)(q0 + qc) * D_DIM + h * 8;
    #pragma unroll
    for (int t = 0; t < 4; ++t) {
      float4 f0 = *reinterpret_cast<const float4*>(qp + t * 16);
      float4 f1 = *reinterpret_cast<const float4*>(qp + t * 16 + 4);
      bf16x8 q;
      q[0]=(__bf16)(f0.x*qsc); q[1]=(__bf16)(f0.y*qsc);
      q[2]=(__bf16)(f0.z*qsc); q[3]=(__bf16)(f0.w*qsc);
      q[4]=(__bf16)(f1.x*qsc); q[5]=(__bf16)(f1.y*qsc);
      q[6]=(__bf16)(f1.z*qsc); q[7]=(__bf16)(f1.w*qsc);
      qf[t] = q;
    }
  }

  f32x16 po0, po1;               // O: rows crow(r,h), cols d = dt*32 + qc
  #pragma unroll
  for (int r = 0; r < 16; ++r) { po0[r] = 0.f; po1[r] = 0.f; }
  float m_run = -1e30f, l_run = 0.f;   // per q = qc (replicated across h)

  const unsigned char* kb_bh = Kb + (long)bh * 64 * 4096 + lane * 16;
  const unsigned char* vt_bh = Vt + (long)bh * 64 * 4096 + lane * 16;

  bf16x8 kfr[4], vfr[4];
  auto ldK = [&](int kt) {
    const unsigned char* p = kb_bh + (long)kt * 4096;
    #pragma unroll
    for (int t = 0; t < 4; ++t)
      kfr[t] = *reinterpret_cast<const bf16x8*>(p + t * 1024);
  };
  auto ldV = [&](int kt) {
    const unsigned char* p = vt_bh + (long)kt * 4096;
    #pragma unroll
    for (int t = 0; t < 4; ++t)
      vfr[t] = *reinterpret_cast<const bf16x8*>(p + t * 1024);
  };

  ldK(0);
  ldV(0);

  for (int kt = 0; kt < NT; ++kt) {
    const bool more = (kt + 1 < NT);

    // S^T via mfma(K, Q): sa[r] = S[k = kt*32 + crow(r,h)][q = q0 + qc]
    f32x16 sa;
    #pragma unroll
    for (int r = 0; r < 16; ++r) sa[r] = 0.f;
    __builtin_amdgcn_s_setprio(1);
    #pragma unroll
    for (int t = 0; t < 4; ++t)
      sa = __builtin_amdgcn_mfma_f32_32x32x16_bf16(kfr[t], qf[t], sa, 0, 0, 0);
    __builtin_amdgcn_s_setprio(0);

    if (more) ldK(kt + 1);   // prefetch next K (lands under softmax+PV)

    if (kt == NT - 1) {      // causal mask: diag tile only; crow > qc => masked
      #pragma unroll
      for (int r = 0; r < 16; ++r)
        if (((r & 3) + 8 * (r >> 2) + 4 * h) > qc) sa[r] = -1e30f;
    }

    // row max: in-lane tree over 16 + cross-half shfl_xor
    float rmax;
    {
      float a0 = fmaxf(fmaxf(sa[0], sa[1]),  fmaxf(sa[2], sa[3]));
      float a1 = fmaxf(fmaxf(sa[4], sa[5]),  fmaxf(sa[6], sa[7]));
      float a2 = fmaxf(fmaxf(sa[8], sa[9]),  fmaxf(sa[10], sa[11]));
      float a3 = fmaxf(fmaxf(sa[12], sa[13]), fmaxf(sa[14], sa[15]));
      rmax = fmaxf(fmaxf(a0, a1), fmaxf(a2, a3));
      rmax = fmaxf(rmax, __shfl_xor(rmax, 32));
    }

    // defer-max (T13): rescale only when running max grew by > 8 (exp2 units)
    if (__any(rmax > m_run + 8.0f)) {
      float mn    = fmaxf(m_run, rmax);
      float alpha = exp2f(m_run - mn);
      m_run = mn;
      l_run *= alpha;
      #pragma unroll
      for (int r = 0; r < 16; ++r) {
        float ar = __shfl(alpha, (r & 3) + 8 * (r >> 2) + 4 * h);
        po0[r] *= ar;
        po1[r] *= ar;
      }
    }

    // P = exp2(S - m) in place; in-lane sum tree + cross-half shfl_xor
    #pragma unroll
    for (int r = 0; r < 16; ++r) sa[r] = exp2f(sa[r] - m_run);
    {
      float s0 = (sa[0] + sa[1]) + (sa[2] + sa[3]);
      float s1 = (sa[4] + sa[5]) + (sa[6] + sa[7]);
      float s2 = (sa[8] + sa[9]) + (sa[10] + sa[11]);
      float s3 = (sa[12] + sa[13]) + (sa[14] + sa[15]);
      float rs = (s0 + s1) + (s2 + s3);
      l_run += rs + __shfl_xor(rs, 32);
    }

    // P -> bf16 PA fragments: cvt_pk pairs + cross-half exchange + select.
    // Lane (qc,h) holds k = {4h..4h+3, 8+4h.., 16+4h.., 24+4h..}; A-frag needs
    // k = h*8 + 0..7 (pa0) and 16 + h*8 + 0..7 (pa1).
    bf16x8 pa0, pa1;
    {
      unsigned k0 = pk2(sa[0], sa[1]),   k1 = pk2(sa[2], sa[3]);
      unsigned k2 = pk2(sa[4], sa[5]),   k3 = pk2(sa[6], sa[7]);
      unsigned k4 = pk2(sa[8], sa[9]),   k5 = pk2(sa[10], sa[11]);
      unsigned k6 = pk2(sa[12], sa[13]), k7 = pk2(sa[14], sa[15]);
      unsigned p0 = (unsigned)__shfl_xor((int)k0, 32);
      unsigned p1 = (unsigned)__shfl_xor((int)k1, 32);
      unsigned p2 = (unsigned)__shfl_xor((int)k2, 32);
      unsigned p3 = (unsigned)__shfl_xor((int)k3, 32);
      unsigned p4 = (unsigned)__shfl_xor((int)k4, 32);
      unsigned p5 = (unsigned)__shfl_xor((int)k5, 32);
      unsigned p6 = (unsigned)__shfl_xor((int)k6, 32);
      unsigned p7 = (unsigned)__shfl_xor((int)k7, 32);
      union { unsigned u[4]; bf16x8 v; } a, b;
      a.u[0] = h ? p2 : k0;  a.u[1] = h ? p3 : k1;   // h=0: {0,1},{2,3}; h=1: {8,9},{10,11}
      a.u[2] = h ? k2 : p0;  a.u[3] = h ? k3 : p1;   // h=0: {4,5},{6,7}; h=1: {12,13},{14,15}
      b.u[0] = h ? p6 : k4;  b.u[1] = h ? p7 : k5;   // h=0: {16,17},{18,19}; h=1: {24,25},..
      b.u[2] = h ? k6 : p4;  b.u[3] = h ? k7 : p5;   // h=0: {20,21},{22,23}; h=1: {28,29},..
      pa0 = a.v;
      pa1 = b.v;
    }

    // O += P V  (A=P frags, B=V frags; no LDS roundtrip)
    __builtin_amdgcn_s_setprio(1);
    po0 = __builtin_amdgcn_mfma_f32_32x32x16_bf16(pa0, vfr[0], po0, 0, 0, 0);
    po0 = __builtin_amdgcn_mfma_f32_32x32x16_bf16(pa1, vfr[1], po0, 0, 0, 0);
    po1 = __builtin_amdgcn_mfma_f32_32x32x16_bf16(pa0, vfr[2], po1, 0, 0, 0);
    po1 = __builtin_amdgcn_mfma_f32_32x32x16_bf16(pa1, vfr[3], po1, 0, 0, 0);
    __builtin_amdgcn_s_setprio(0);

    if (more) ldV(kt + 1);   // prefetch next V (lands under next QK+softmax)
  }

  // epilogue: gather 1/l per row, store fp32
  #pragma unroll
  for (int r = 0; r < 16; ++r) {
    int crow = (r & 3) + 8 * (r >> 2) + 4 * h;
    float iv = 1.0f / __shfl(l_run, crow);
    long rowoff = base + (long)(q0 + crow) * D_DIM + qc;
    Og[rowoff]      = po0[r] * iv;
    Og[rowoff + 32] = po1[r] * iv;
  }
}

// ---------------- fallback (round-5 kernel) if ws too small ----------------
__global__ __launch_bounds__(256) void attn_fwd_fallback(
    const float* __restrict__ Vg, const float* __restrict__ Qg,
    const float* __restrict__ Kg, float* __restrict__ Og) {
  __shared__ __align__(16) unsigned char k_lds[64 * 128];
  __shared__ __align__(16) unsigned char vt_lds[64 * 128];
  __shared__ __align__(16) unsigned char p_lds[4][16 * 128];

  const int tid  = threadIdx.x;
  const int lane = tid & 63;
  const int w    = tid >> 6;
  const int lr   = lane & 15;
  const int lg   = lane >> 4;
  const int swz  = (lr & 7) << 4;

  const int lb = blockIdx.x;
  const int e  = lb & 7;
  const int s  = lb >> 3;
  const int bh = e + 8 * (s >> 5);
  const int qs = s & 31;
  const int qt = (qs & 1) ? (NQT - 1 - (qs >> 1)) : (qs >> 1);
  const long base = (long)bh * (S_LEN * D_DIM);
  const int q0 = qt * 64;

  bf16x8 qf[2];
  {
    const float qsc = 0.125f * 1.44269504f;
    const float* qp = Qg + base + (q0 + w * 16 + lr) * D_DIM + lg * 8;
    #pragma unroll
    for (int c = 0; c < 2; ++c) {
      float4 f0 = *reinterpret_cast<const float4*>(qp + c * 32);
      float4 f1 = *reinterpret_cast<const float4*>(qp + c * 32 + 4);
      bf16x8 t;
      t[0]=(__bf16)(f0.x*qsc); t[1]=(__bf16)(f0.y*qsc);
      t[2]=(__bf16)(f0.z*qsc); t[3]=(__bf16)(f0.w*qsc);
      t[4]=(__bf16)(f1.x*qsc); t[5]=(__bf16)(f1.y*qsc);
      t[6]=(__bf16)(f1.z*qsc); t[7]=(__bf16)(f1.w*qsc);
      qf[c] = t;
    }
  }
  bf16x8 onesf;
  #pragma unroll
  for (int j = 0; j < 8; ++j) onesf[j] = (lr == 0) ? (__bf16)1.0f : (__bf16)0.0f;

  f32x4 po[4], pl;
  float m_run = -1e30f;
  #pragma unroll
  for (int j = 0; j < 4; ++j) po[j] = (f32x4){0.f,0.f,0.f,0.f};
  pl = (f32x4){0.f,0.f,0.f,0.f};

  float4 kreg[4];
  float  vreg[16];
  const int d_ = lane;
  const int kb = w;

  auto load_regs = [&](int kt) {
    const float* kg = Kg + base + kt * (64 * D_DIM);
    #pragma unroll
    for (int i = 0; i < 4; ++i) {
      int idx = tid + 256 * i;
      int r = idx >> 4, f4 = idx & 15;
      kreg[i] = *reinterpret_cast<const float4*>(kg + r * 64 + f4 * 4);
    }
    const float* vg = Vg + base + kt * (64 * D_DIM);
    #pragma unroll
    for (int j = 0; j < 8; ++j) {
      vreg[j]     = vg[(kb * 8 + j) * 64 + d_];
      vreg[8 + j] = vg[((kb + 4) * 8 + j) * 64 + d_];
    }
  };
  auto write_buf = [&]() {
    #pragma unroll
    for (int i = 0; i < 4; ++i) {
      int idx = tid + 256 * i;
      int r = idx >> 4, f4 = idx & 15;
      bf16x4 t;
      t[0]=(__bf16)kreg[i].x; t[1]=(__bf16)kreg[i].y;
      t[2]=(__bf16)kreg[i].z; t[3]=(__bf16)kreg[i].w;
      int b = r * 128 + ((f4 * 8) ^ ((r & 7) << 4));
      *reinterpret_cast<bf16x4*>(&k_lds[b]) = t;
    }
    bf16x8 t0, t1;
    #pragma unroll
    for (int j = 0; j < 8; ++j) { t0[j] = (__bf16)vreg[j]; t1[j] = (__bf16)vreg[8+j]; }
    int b0 = d_ * 128 + ((kb * 16) ^ ((d_ & 7) << 4));
    int b1 = d_ * 128 + (((kb + 4) * 16) ^ ((d_ & 7) << 4));
    *reinterpret_cast<bf16x8*>(&vt_lds[b0]) = t0;
    *reinterpret_cast<bf16x8*>(&vt_lds[b1]) = t1;
  };

  load_regs(0);
  write_buf();
  __syncthreads();

  for (int kt = 0; kt <= qt; ++kt) {
    const bool last = (kt == qt);
    if (!last) load_regs(kt + 1);

    f32x4 sa[4];
    #pragma unroll
    for (int ct = 0; ct < 4; ++ct) sa[ct] = (f32x4){0.f,0.f,0.f,0.f};
    #pragma unroll
    for (int ct = 0; ct < 4; ++ct) {
      #pragma unroll
      for (int c = 0; c < 2; ++c) {
        int b = (ct * 16 + lr) * 128 + ((lg * 16 + c * 64) ^ swz);
        bf16x8 kf = *reinterpret_cast<const bf16x8*>(&k_lds[b]);
        sa[ct] = __builtin_amdgcn_mfma_f32_16x16x32_bf16(kf, qf[c], sa[ct], 0, 0, 0);
      }
    }
    if (last) {
      #pragma unroll
      for (int ct = 0; ct < 4; ++ct)
        #pragma unroll
        for (int j = 0; j < 4; ++j)
          if (ct * 16 + lg * 4 + j > w * 16 + lr) sa[ct][j] = -1e30f;
    }
    float rmax = sa[0][0];
    #pragma unroll
    for (int ct = 0; ct < 4; ++ct)
      #pragma unroll
      for (int j = 0; j < 4; ++j) rmax = fmaxf(rmax, sa[ct][j]);
    rmax = fmaxf(rmax, __shfl_xor(rmax, 16));
    rmax = fmaxf(rmax, __shfl_xor(rmax, 32));
    float mn    = fmaxf(m_run, rmax);
    float alpha = exp2f(m_run - mn);
    m_run = mn;
    #pragma unroll
    for (int ct = 0; ct < 4; ++ct) {
      bf16x4 t;
      #pragma unroll
      for (int j = 0; j < 4; ++j) t[j] = (__bf16)exp2f(sa[ct][j] - mn);
      int b = lr * 128 + ((ct * 32 + lg * 8) ^ swz);
      *reinterpret_cast<bf16x4*>(&p_lds[w][b]) = t;
    }
    float aj[4];
    #pragma unroll
    for (int j = 0; j < 4; ++j) aj[j] = __shfl(alpha, (lane & 48) | (lg * 4 + j));
    #pragma unroll
    for (int j = 0; j < 4; ++j) {
      pl[j] *= aj[j];
      #pragma unroll
      for (int dt = 0; dt < 4; ++dt) po[dt][j] *= aj[j];
    }
    #pragma unroll
    for (int c = 0; c < 2; ++c) {
      int ab = lr * 128 + ((lg * 16 + c * 64) ^ swz);
      bf16x8 pa = *reinterpret_cast<const bf16x8*>(&p_lds[w][ab]);
      pl = __builtin_amdgcn_mfma_f32_16x16x32_bf16(pa, onesf, pl, 0, 0, 0);
      #pragma unroll
      for (int dt = 0; dt < 4; ++dt) {
        int vb_ = (dt * 16 + lr) * 128 + ((lg * 16 + c * 64) ^ swz);
        bf16x8 vb = *reinterpret_cast<const bf16x8*>(&vt_lds[vb_]);
        po[dt] = __builtin_amdgcn_mfma_f32_16x16x32_bf16(pa, vb, po[dt], 0, 0, 0);
      }
    }
    if (!last) {
      __syncthreads();
      write_buf();
      __syncthreads();
    }
  }
  #pragma unroll
  for (int j = 0; j < 4; ++j) {
    float lv  = __shfl(pl[j], lane & 48);
    float inv = 1.0f / lv;
    int row = q0 + w * 16 + lg * 4 + j;
    #pragma unroll
    for (int dt = 0; dt < 4; ++dt)
      Og[base + row * D_DIM + dt * 16 + lr] = po[dt][j] * inv;
  }
}

extern "C" void kernel_launch(void* const* d_in, const int* in_sizes, int n_in,
                              void* d_out, int out_size, void* d_ws, size_t ws_size,
                              hipStream_t stream) {
  const float* V = (const float*)d_in[0];
  const float* Q = (const float*)d_in[1];
  const float* K = (const float*)d_in[2];
  float* O = (float*)d_out;
  const size_t need = (size_t)2 * 32 * 64 * 4096;  // Kb + Vt = 16 MB
  if (ws_size >= need) {
    unsigned char* Kb = (unsigned char*)d_ws;
    unsigned char* Vt = Kb + (size_t)32 * 64 * 4096;
    preprocess_kernel<<<dim3(2048), dim3(256), 0, stream>>>(K, V, Kb, Vt);
    attn_fwd_w32<<<dim3(2048), dim3(64), 0, stream>>>(Q, Kb, Vt, O);
  } else {
    attn_fwd_fallback<<<dim3(1024), dim3(256), 0, stream>>>(V, Q, K, O);
  }
}

// Round 12
// 62.422 us; speedup vs baseline: 1.2879x; 1.2879x over previous
//
#include <hip/hip_runtime.h>
#include <hip/hip_bf16.h>

typedef __bf16 bf16x8 __attribute__((ext_vector_type(8)));
typedef __bf16 bf16x4 __attribute__((ext_vector_type(4)));
typedef __bf16 bf16x2 __attribute__((ext_vector_type(2)));
typedef float f32x4 __attribute__((ext_vector_type(4)));
typedef float f32x16 __attribute__((ext_vector_type(16)));

#define S_LEN 2048
#define D_DIM 64
#define NQT   32

// pack two f32 -> u32 of 2 bf16 (compiler fuses to v_cvt_pk_bf16_f32)
static __device__ __forceinline__ unsigned pk2(float a, float b) {
  bf16x2 t; t[0] = (__bf16)a; t[1] = (__bf16)b;
  return __builtin_bit_cast(unsigned, t);
}

// ---------------- preprocess: 32x32-MFMA fragment images (r11-verified) ----------------
__global__ __launch_bounds__(256) void preprocess_kernel(
    const float* __restrict__ Kg, const float* __restrict__ Vg,
    unsigned char* __restrict__ Kb, unsigned char* __restrict__ Vt) {
  __shared__ float buf[2048];   // 8 KB: one 32x64 fp32 tile
  const int tid  = threadIdx.x;
  const int tile = blockIdx.x;          // bh*64 + kt
  const float* kg = Kg + (long)tile * 2048;
  const float* vg = Vg + (long)tile * 2048;
  unsigned char* kb = Kb + (long)tile * 4096;
  unsigned char* vt = Vt + (long)tile * 4096;

  const int l = tid & 63, f = tid >> 6, h = l >> 5;

  {
    const float* kr = kg + (l & 31) * 64 + f * 16 + h * 8;
    float4 a = *reinterpret_cast<const float4*>(kr);
    float4 b = *reinterpret_cast<const float4*>(kr + 4);
    bf16x8 t;
    t[0]=(__bf16)a.x; t[1]=(__bf16)a.y; t[2]=(__bf16)a.z; t[3]=(__bf16)a.w;
    t[4]=(__bf16)b.x; t[5]=(__bf16)b.y; t[6]=(__bf16)b.z; t[7]=(__bf16)b.w;
    *reinterpret_cast<bf16x8*>(kb + tid * 16) = t;
  }
  #pragma unroll
  for (int i = 0; i < 2; ++i) {
    int idx = tid + 256 * i;
    *reinterpret_cast<float4*>(buf + idx * 4) =
        *reinterpret_cast<const float4*>(vg + idx * 4);
  }
  __syncthreads();
  {
    int dt = f >> 1, ks = f & 1;
    int d  = dt * 32 + (l & 31);
    int k0 = ks * 16 + h * 8;
    bf16x8 t;
    #pragma unroll
    for (int j = 0; j < 8; ++j) t[j] = (__bf16)buf[(k0 + j) * 64 + d];
    *reinterpret_cast<bf16x8*>(vt + tid * 16) = t;
  }
}

// ---------------- main: 2-wave split-K blocks, 32x32 MFMA, register softmax ----------------
// Block = 128 threads = 2 waves on the SAME 32-row q-group; wave w handles
// k-tiles kt = w, w+2, ... with private (m,l,O); one LDS flash-merge at the
// end. Per-tile math byte-identical to r11 (verified). Reshape uses 4
// shfl_xor (pre-select per half serves both output slots).
__global__ __launch_bounds__(128, 4) void attn_fwd_w32s(
    const float* __restrict__ Qg, const unsigned char* __restrict__ Kb,
    const unsigned char* __restrict__ Vt, float* __restrict__ Og) {
  __shared__ float o_sm[2][32][68];   // 17408 B (stride 68: 16B-aligned rows)
  __shared__ float m_sm[2][32];
  __shared__ float l_sm[2][32];

  const int tid  = threadIdx.x;
  const int lane = tid & 63;
  const int w    = tid >> 6;     // wave 0..1 (k-parity)
  const int qc   = lane & 31;    // q column this lane tracks
  const int h    = lane >> 5;

  // decode: XCD-clustered bh (4 bh per XCD), longest q-groups first (LPT)
  const int lb = blockIdx.x;            // 0..2047
  const int e  = lb & 7;
  const int s  = lb >> 3;               // 0..255
  const int bh = e + 8 * (s >> 6);      // 4 bh per XCD
  const int qg = 63 - (s & 63);         // q-group of 32 rows, longest first
  const long base = (long)bh * (S_LEN * D_DIM);
  const int q0 = qg * 32;
  const int NT = qg + 1;                // # of 32-wide k-tiles

  // Q fragments (B-operand), prescaled by 1/8 * log2(e); same for both waves
  bf16x8 qf[4];
  {
    const float qsc = 0.125f * 1.44269504f;
    const float* qp = Qg + base + (long)(q0 + qc) * D_DIM + h * 8;
    #pragma unroll
    for (int t = 0; t < 4; ++t) {
      float4 f0 = *reinterpret_cast<const float4*>(qp + t * 16);
      float4 f1 = *reinterpret_cast<const float4*>(qp + t * 16 + 4);
      bf16x8 q;
      q[0]=(__bf16)(f0.x*qsc); q[1]=(__bf16)(f0.y*qsc);
      q[2]=(__bf16)(f0.z*qsc); q[3]=(__bf16)(f0.w*qsc);
      q[4]=(__bf16)(f1.x*qsc); q[5]=(__bf16)(f1.y*qsc);
      q[6]=(__bf16)(f1.z*qsc); q[7]=(__bf16)(f1.w*qsc);
      qf[t] = q;
    }
  }

  f32x16 po0, po1;               // O partial: rows crow(r,h), cols d = dt*32 + qc
  #pragma unroll
  for (int r = 0; r < 16; ++r) { po0[r] = 0.f; po1[r] = 0.f; }
  float m_run = -1e30f, l_run = 0.f;   // per q = qc (replicated across h)

  const unsigned char* kb_bh = Kb + (long)bh * 64 * 4096 + lane * 16;
  const unsigned char* vt_bh = Vt + (long)bh * 64 * 4096 + lane * 16;

  bf16x8 kfr[4], vfr[4];
  auto ldK = [&](int kt) {
    const unsigned char* p = kb_bh + (long)kt * 4096;
    #pragma unroll
    for (int t = 0; t < 4; ++t)
      kfr[t] = *reinterpret_cast<const bf16x8*>(p + t * 1024);
  };
  auto ldV = [&](int kt) {
    const unsigned char* p = vt_bh + (long)kt * 4096;
    #pragma unroll
    for (int t = 0; t < 4; ++t)
      vfr[t] = *reinterpret_cast<const bf16x8*>(p + t * 1024);
  };

  ldK(w);   // tile index w always exists in the bh buffer (64 tiles)
  ldV(w);

  for (int kt = w; kt < NT; kt += 2) {
    const bool more = (kt + 2 < NT);

    // S^T via mfma(K, Q): sa[r] = S[k = kt*32 + crow(r,h)][q = q0 + qc]
    f32x16 sa;
    #pragma unroll
    for (int r = 0; r < 16; ++r) sa[r] = 0.f;
    __builtin_amdgcn_s_setprio(1);
    #pragma unroll
    for (int t = 0; t < 4; ++t)
      sa = __builtin_amdgcn_mfma_f32_32x32x16_bf16(kfr[t], qf[t], sa, 0, 0, 0);
    __builtin_amdgcn_s_setprio(0);

    if (more) ldK(kt + 2);   // prefetch next K (lands under softmax+PV)

    if (kt == NT - 1) {      // causal mask: diag tile only; crow > qc => masked
      #pragma unroll
      for (int r = 0; r < 16; ++r)
        if (((r & 3) + 8 * (r >> 2) + 4 * h) > qc) sa[r] = -1e30f;
    }

    // row max: in-lane tree over 16 + cross-half shfl_xor
    float rmax;
    {
      float a0 = fmaxf(fmaxf(sa[0], sa[1]),  fmaxf(sa[2], sa[3]));
      float a1 = fmaxf(fmaxf(sa[4], sa[5]),  fmaxf(sa[6], sa[7]));
      float a2 = fmaxf(fmaxf(sa[8], sa[9]),  fmaxf(sa[10], sa[11]));
      float a3 = fmaxf(fmaxf(sa[12], sa[13]), fmaxf(sa[14], sa[15]));
      rmax = fmaxf(fmaxf(a0, a1), fmaxf(a2, a3));
      rmax = fmaxf(rmax, __shfl_xor(rmax, 32));
    }

    // defer-max (T13): rescale only when running max grew by > 8 (exp2 units)
    if (__any(rmax > m_run + 8.0f)) {
      float mn    = fmaxf(m_run, rmax);
      float alpha = exp2f(m_run - mn);
      m_run = mn;
      l_run *= alpha;
      #pragma unroll
      for (int r = 0; r < 16; ++r) {
        float ar = __shfl(alpha, (r & 3) + 8 * (r >> 2) + 4 * h);
        po0[r] *= ar;
        po1[r] *= ar;
      }
    }

    // P = exp2(S - m); in-lane sum tree + cross-half shfl_xor
    #pragma unroll
    for (int r = 0; r < 16; ++r) sa[r] = exp2f(sa[r] - m_run);
    {
      float s0 = (sa[0] + sa[1]) + (sa[2] + sa[3]);
      float s1 = (sa[4] + sa[5]) + (sa[6] + sa[7]);
      float s2 = (sa[8] + sa[9]) + (sa[10] + sa[11]);
      float s3 = (sa[12] + sa[13]) + (sa[14] + sa[15]);
      float rs = (s0 + s1) + (s2 + s3);
      l_run += rs + __shfl_xor(rs, 32);
    }

    // P -> bf16 PA fragments (r11-verified mapping, 4 shfl_xor):
    // pre-select what each half sends so one exchange serves both slots.
    bf16x8 pa0, pa1;
    {
      unsigned k0 = pk2(sa[0], sa[1]),   k1 = pk2(sa[2], sa[3]);
      unsigned k2 = pk2(sa[4], sa[5]),   k3 = pk2(sa[6], sa[7]);
      unsigned k4 = pk2(sa[8], sa[9]),   k5 = pk2(sa[10], sa[11]);
      unsigned k6 = pk2(sa[12], sa[13]), k7 = pk2(sa[14], sa[15]);
      unsigned x02 = h ? k0 : k2, x13 = h ? k1 : k3;
      unsigned x46 = h ? k4 : k6, x57 = h ? k5 : k7;
      unsigned p02 = (unsigned)__shfl_xor((int)x02, 32);
      unsigned p13 = (unsigned)__shfl_xor((int)x13, 32);
      unsigned p46 = (unsigned)__shfl_xor((int)x46, 32);
      unsigned p57 = (unsigned)__shfl_xor((int)x57, 32);
      union { unsigned u[4]; bf16x8 v; } a, b;
      a.u[0] = h ? p02 : k0;  a.u[1] = h ? p13 : k1;
      a.u[2] = h ? k2 : p02;  a.u[3] = h ? k3 : p13;
      b.u[0] = h ? p46 : k4;  b.u[1] = h ? p57 : k5;
      b.u[2] = h ? k6 : p46;  b.u[3] = h ? k7 : p57;
      pa0 = a.v;
      pa1 = b.v;
    }

    // O += P V (no LDS roundtrip)
    __builtin_amdgcn_s_setprio(1);
    po0 = __builtin_amdgcn_mfma_f32_32x32x16_bf16(pa0, vfr[0], po0, 0, 0, 0);
    po0 = __builtin_amdgcn_mfma_f32_32x32x16_bf16(pa1, vfr[1], po0, 0, 0, 0);
    po1 = __builtin_amdgcn_mfma_f32_32x32x16_bf16(pa0, vfr[2], po1, 0, 0, 0);
    po1 = __builtin_amdgcn_mfma_f32_32x32x16_bf16(pa1, vfr[3], po1, 0, 0, 0);
    __builtin_amdgcn_s_setprio(0);

    if (more) ldV(kt + 2);   // prefetch next V
  }

  // ---- write partials, flash-merge the two waves ----
  #pragma unroll
  for (int r = 0; r < 16; ++r) {
    int crow = (r & 3) + 8 * (r >> 2) + 4 * h;
    o_sm[w][crow][qc]      = po0[r];
    o_sm[w][crow][qc + 32] = po1[r];
  }
  if (h == 0) { m_sm[w][qc] = m_run; l_sm[w][qc] = l_run; }
  __syncthreads();

  {
    const int q  = tid >> 2;          // 0..31
    const int d0 = (tid & 3) * 16;    // 0,16,32,48
    float m0 = m_sm[0][q], m1 = m_sm[1][q];
    float M  = fmaxf(m0, m1);
    float a0 = exp2f(m0 - M), a1 = exp2f(m1 - M);
    float inv = 1.0f / (a0 * l_sm[0][q] + a1 * l_sm[1][q]);
    const float* r0 = &o_sm[0][q][d0];
    const float* r1 = &o_sm[1][q][d0];
    float* og = Og + base + (long)(q0 + q) * D_DIM + d0;
    #pragma unroll
    for (int i = 0; i < 4; ++i) {
      float4 x0 = *reinterpret_cast<const float4*>(r0 + 4 * i);
      float4 x1 = *reinterpret_cast<const float4*>(r1 + 4 * i);
      float4 o;
      o.x = (a0 * x0.x + a1 * x1.x) * inv;
      o.y = (a0 * x0.y + a1 * x1.y) * inv;
      o.z = (a0 * x0.z + a1 * x1.z) * inv;
      o.w = (a0 * x0.w + a1 * x1.w) * inv;
      *reinterpret_cast<float4*>(og + 4 * i) = o;
    }
  }
}

// ---------------- fallback (round-5 kernel) if ws too small ----------------
__global__ __launch_bounds__(256) void attn_fwd_fallback(
    const float* __restrict__ Vg, const float* __restrict__ Qg,
    const float* __restrict__ Kg, float* __restrict__ Og) {
  __shared__ __align__(16) unsigned char k_lds[64 * 128];
  __shared__ __align__(16) unsigned char vt_lds[64 * 128];
  __shared__ __align__(16) unsigned char p_lds[4][16 * 128];

  const int tid  = threadIdx.x;
  const int lane = tid & 63;
  const int w    = tid >> 6;
  const int lr   = lane & 15;
  const int lg   = lane >> 4;
  const int swz  = (lr & 7) << 4;

  const int lb = blockIdx.x;
  const int e  = lb & 7;
  const int s  = lb >> 3;
  const int bh = e + 8 * (s >> 5);
  const int qs = s & 31;
  const int qt = (qs & 1) ? (NQT - 1 - (qs >> 1)) : (qs >> 1);
  const long base = (long)bh * (S_LEN * D_DIM);
  const int q0 = qt * 64;

  bf16x8 qf[2];
  {
    const float qsc = 0.125f * 1.44269504f;
    const float* qp = Qg + base + (q0 + w * 16 + lr) * D_DIM + lg * 8;
    #pragma unroll
    for (int c = 0; c < 2; ++c) {
      float4 f0 = *reinterpret_cast<const float4*>(qp + c * 32);
      float4 f1 = *reinterpret_cast<const float4*>(qp + c * 32 + 4);
      bf16x8 t;
      t[0]=(__bf16)(f0.x*qsc); t[1]=(__bf16)(f0.y*qsc);
      t[2]=(__bf16)(f0.z*qsc); t[3]=(__bf16)(f0.w*qsc);
      t[4]=(__bf16)(f1.x*qsc); t[5]=(__bf16)(f1.y*qsc);
      t[6]=(__bf16)(f1.z*qsc); t[7]=(__bf16)(f1.w*qsc);
      qf[c] = t;
    }
  }
  bf16x8 onesf;
  #pragma unroll
  for (int j = 0; j < 8; ++j) onesf[j] = (lr == 0) ? (__bf16)1.0f : (__bf16)0.0f;

  f32x4 po[4], pl;
  float m_run = -1e30f;
  #pragma unroll
  for (int j = 0; j < 4; ++j) po[j] = (f32x4){0.f,0.f,0.f,0.f};
  pl = (f32x4){0.f,0.f,0.f,0.f};

  float4 kreg[4];
  float  vreg[16];
  const int d_ = lane;
  const int kb = w;

  auto load_regs = [&](int kt) {
    const float* kg = Kg + base + kt * (64 * D_DIM);
    #pragma unroll
    for (int i = 0; i < 4; ++i) {
      int idx = tid + 256 * i;
      int r = idx >> 4, f4 = idx & 15;
      kreg[i] = *reinterpret_cast<const float4*>(kg + r * 64 + f4 * 4);
    }
    const float* vg = Vg + base + kt * (64 * D_DIM);
    #pragma unroll
    for (int j = 0; j < 8; ++j) {
      vreg[j]     = vg[(kb * 8 + j) * 64 + d_];
      vreg[8 + j] = vg[((kb + 4) * 8 + j) * 64 + d_];
    }
  };
  auto write_buf = [&]() {
    #pragma unroll
    for (int i = 0; i < 4; ++i) {
      int idx = tid + 256 * i;
      int r = idx >> 4, f4 = idx & 15;
      bf16x4 t;
      t[0]=(__bf16)kreg[i].x; t[1]=(__bf16)kreg[i].y;
      t[2]=(__bf16)kreg[i].z; t[3]=(__bf16)kreg[i].w;
      int b = r * 128 + ((f4 * 8) ^ ((r & 7) << 4));
      *reinterpret_cast<bf16x4*>(&k_lds[b]) = t;
    }
    bf16x8 t0, t1;
    #pragma unroll
    for (int j = 0; j < 8; ++j) { t0[j] = (__bf16)vreg[j]; t1[j] = (__bf16)vreg[8+j]; }
    int b0 = d_ * 128 + ((kb * 16) ^ ((d_ & 7) << 4));
    int b1 = d_ * 128 + (((kb + 4) * 16) ^ ((d_ & 7) << 4));
    *reinterpret_cast<bf16x8*>(&vt_lds[b0]) = t0;
    *reinterpret_cast<bf16x8*>(&vt_lds[b1]) = t1;
  };

  load_regs(0);
  write_buf();
  __syncthreads();

  for (int kt = 0; kt <= qt; ++kt) {
    const bool last = (kt == qt);
    if (!last) load_regs(kt + 1);

    f32x4 sa[4];
    #pragma unroll
    for (int ct = 0; ct < 4; ++ct) sa[ct] = (f32x4){0.f,0.f,0.f,0.f};
    #pragma unroll
    for (int ct = 0; ct < 4; ++ct) {
      #pragma unroll
      for (int c = 0; c < 2; ++c) {
        int b = (ct * 16 + lr) * 128 + ((lg * 16 + c * 64) ^ swz);
        bf16x8 kf = *reinterpret_cast<const bf16x8*>(&k_lds[b]);
        sa[ct] = __builtin_amdgcn_mfma_f32_16x16x32_bf16(kf, qf[c], sa[ct], 0, 0, 0);
      }
    }
    if (last) {
      #pragma unroll
      for (int ct = 0; ct < 4; ++ct)
        #pragma unroll
        for (int j = 0; j < 4; ++j)
          if (ct * 16 + lg * 4 + j > w * 16 + lr) sa[ct][j] = -1e30f;
    }
    float rmax = sa[0][0];
    #pragma unroll
    for (int ct = 0; ct < 4; ++ct)
      #pragma unroll
      for (int j = 0; j < 4; ++j) rmax = fmaxf(rmax, sa[ct][j]);
    rmax = fmaxf(rmax, __shfl_xor(rmax, 16));
    rmax = fmaxf(rmax, __shfl_xor(rmax, 32));
    float mn    = fmaxf(m_run, rmax);
    float alpha = exp2f(m_run - mn);
    m_run = mn;
    #pragma unroll
    for (int ct = 0; ct < 4; ++ct) {
      bf16x4 t;
      #pragma unroll
      for (int j = 0; j < 4; ++j) t[j] = (__bf16)exp2f(sa[ct][j] - mn);
      int b = lr * 128 + ((ct * 32 + lg * 8) ^ swz);
      *reinterpret_cast<bf16x4*>(&p_lds[w][b]) = t;
    }
    float aj[4];
    #pragma unroll
    for (int j = 0; j < 4; ++j) aj[j] = __shfl(alpha, (lane & 48) | (lg * 4 + j));
    #pragma unroll
    for (int j = 0; j < 4; ++j) {
      pl[j] *= aj[j];
      #pragma unroll
      for (int dt = 0; dt < 4; ++dt) po[dt][j] *= aj[j];
    }
    #pragma unroll
    for (int c = 0; c < 2; ++c) {
      int ab = lr * 128 + ((lg * 16 + c * 64) ^ swz);
      bf16x8 pa = *reinterpret_cast<const bf16x8*>(&p_lds[w][ab]);
      pl = __builtin_amdgcn_mfma_f32_16x16x32_bf16(pa, onesf, pl, 0, 0, 0);
      #pragma unroll
      for (int dt = 0; dt < 4; ++dt) {
        int vb_ = (dt * 16 + lr) * 128 + ((lg * 16 + c * 64) ^ swz);
        bf16x8 vb = *reinterpret_cast<const bf16x8*>(&vt_lds[vb_]);
        po[dt] = __builtin_amdgcn_mfma_f32_16x16x32_bf16(pa, vb, po[dt], 0, 0, 0);
      }
    }
    if (!last) {
      __syncthreads();
      write_buf();
      __syncthreads();
    }
  }
  #pragma unroll
  for (int j = 0; j < 4; ++j) {
    float lv  = __shfl(pl[j], lane & 48);
    float inv = 1.0f / lv;
    int row = q0 + w * 16 + lg * 4 + j;
    #pragma unroll
    for (int dt = 0; dt < 4; ++dt)
      Og[base + row * D_DIM + dt * 16 + lr] = po[dt][j] * inv;
  }
}

extern "C" void kernel_launch(void* const* d_in, const int* in_sizes, int n_in,
                              void* d_out, int out_size, void* d_ws, size_t ws_size,
                              hipStream_t stream) {
  const float* V = (const float*)d_in[0];
  const float* Q = (const float*)d_in[1];
  const float* K = (const float*)d_in[2];
  float* O = (float*)d_out;
  const size_t need = (size_t)2 * 32 * 64 * 4096;  // Kb + Vt = 16 MB
  if (ws_size >= need) {
    unsigned char* Kb = (unsigned char*)d_ws;
    unsigned char* Vt = Kb + (size_t)32 * 64 * 4096;
    preprocess_kernel<<<dim3(2048), dim3(256), 0, stream>>>(K, V, Kb, Vt);
    attn_fwd_w32s<<<dim3(2048), dim3(128), 0, stream>>>(Q, Kb, Vt, O);
  } else {
    attn_fwd_fallback<<<dim3(1024), dim3(256), 0, stream>>>(V, Q, K, O);
  }
}

// Round 13
// 61.905 us; speedup vs baseline: 1.2987x; 1.0083x over previous
//
#include <hip/hip_runtime.h>
#include <hip/hip_bf16.h>

typedef __bf16 bf16x8 __attribute__((ext_vector_type(8)));
typedef __bf16 bf16x4 __attribute__((ext_vector_type(4)));
typedef __bf16 bf16x2 __attribute__((ext_vector_type(2)));
typedef float f32x4 __attribute__((ext_vector_type(4)));
typedef float f32x16 __attribute__((ext_vector_type(16)));

#define S_LEN 2048
#define D_DIM 64
#define NQT   32

// pack two f32 -> u32 of 2 bf16 (compiler fuses to v_cvt_pk_bf16_f32)
static __device__ __forceinline__ unsigned pk2(float a, float b) {
  bf16x2 t; t[0] = (__bf16)a; t[1] = (__bf16)b;
  return __builtin_bit_cast(unsigned, t);
}

// ---------------- preprocess: 32x32-MFMA fragment images (r11-verified) ----------------
__global__ __launch_bounds__(256) void preprocess_kernel(
    const float* __restrict__ Kg, const float* __restrict__ Vg,
    unsigned char* __restrict__ Kb, unsigned char* __restrict__ Vt) {
  __shared__ float buf[2048];   // 8 KB: one 32x64 fp32 tile
  const int tid  = threadIdx.x;
  const int tile = blockIdx.x;          // bh*64 + kt
  const float* kg = Kg + (long)tile * 2048;
  const float* vg = Vg + (long)tile * 2048;
  unsigned char* kb = Kb + (long)tile * 4096;
  unsigned char* vt = Vt + (long)tile * 4096;

  const int l = tid & 63, f = tid >> 6, h = l >> 5;

  {
    const float* kr = kg + (l & 31) * 64 + f * 16 + h * 8;
    float4 a = *reinterpret_cast<const float4*>(kr);
    float4 b = *reinterpret_cast<const float4*>(kr + 4);
    bf16x8 t;
    t[0]=(__bf16)a.x; t[1]=(__bf16)a.y; t[2]=(__bf16)a.z; t[3]=(__bf16)a.w;
    t[4]=(__bf16)b.x; t[5]=(__bf16)b.y; t[6]=(__bf16)b.z; t[7]=(__bf16)b.w;
    *reinterpret_cast<bf16x8*>(kb + tid * 16) = t;
  }
  #pragma unroll
  for (int i = 0; i < 2; ++i) {
    int idx = tid + 256 * i;
    *reinterpret_cast<float4*>(buf + idx * 4) =
        *reinterpret_cast<const float4*>(vg + idx * 4);
  }
  __syncthreads();
  {
    int dt = f >> 1, ks = f & 1;
    int d  = dt * 32 + (l & 31);
    int k0 = ks * 16 + h * 8;
    bf16x8 t;
    #pragma unroll
    for (int j = 0; j < 8; ++j) t[j] = (__bf16)buf[(k0 + j) * 64 + d];
    *reinterpret_cast<bf16x8*>(vt + tid * 16) = t;
  }
}

// ---------------- main: balanced pair-blocks, split-K x4, 32x32 MFMA ----------------
// Block = 256 threads = 4 waves handles q-group pair (pi, 63-pi): exactly 65
// tile-iters per block -> zero drain. Two sequential phases; in each, wave w
// takes k-tiles kt = w (mod 4) with private (m,l,O), then a 4-way LDS
// flash-merge. Per-tile math byte-identical to r12 (verified).
__global__ __launch_bounds__(256, 4) void attn_fwd_pair(
    const float* __restrict__ Qg, const unsigned char* __restrict__ Kb,
    const unsigned char* __restrict__ Vt, float* __restrict__ Og) {
  __shared__ float o_sm[4][32][68];   // 34816 B
  __shared__ float m_sm[4][32];
  __shared__ float l_sm[4][32];

  const int tid  = threadIdx.x;
  const int lane = tid & 63;
  const int w    = tid >> 6;     // wave 0..3 (k-residue)
  const int qc   = lane & 31;
  const int h    = lane >> 5;

  // decode: XCD-clustered bh (4 bh per XCD); pair index pi
  const int lb = blockIdx.x;            // 0..1023
  const int e  = lb & 7;
  const int s  = lb >> 3;               // 0..127
  const int bh = e + 8 * (s >> 5);      // 4 bh per XCD
  const int pi = s & 31;
  const long base = (long)bh * (S_LEN * D_DIM);

  const unsigned char* kb_bh = Kb + (long)bh * 64 * 4096 + lane * 16;
  const unsigned char* vt_bh = Vt + (long)bh * 64 * 4096 + lane * 16;

  bf16x8 kfr[4], vfr[4];
  auto ldK = [&](int kt) {
    const unsigned char* p = kb_bh + (long)kt * 4096;
    #pragma unroll
    for (int t = 0; t < 4; ++t)
      kfr[t] = *reinterpret_cast<const bf16x8*>(p + t * 1024);
  };
  auto ldV = [&](int kt) {
    const unsigned char* p = vt_bh + (long)kt * 4096;
    #pragma unroll
    for (int t = 0; t < 4; ++t)
      vfr[t] = *reinterpret_cast<const bf16x8*>(p + t * 1024);
  };

  #pragma unroll
  for (int phase = 0; phase < 2; ++phase) {
    const int qg = phase ? pi : (63 - pi);
    const int q0 = qg * 32;
    const int NT = qg + 1;

    // Q fragments (B-operand), prescaled by 1/8 * log2(e)
    bf16x8 qf[4];
    {
      const float qsc = 0.125f * 1.44269504f;
      const float* qp = Qg + base + (long)(q0 + qc) * D_DIM + h * 8;
      #pragma unroll
      for (int t = 0; t < 4; ++t) {
        float4 f0 = *reinterpret_cast<const float4*>(qp + t * 16);
        float4 f1 = *reinterpret_cast<const float4*>(qp + t * 16 + 4);
        bf16x8 q;
        q[0]=(__bf16)(f0.x*qsc); q[1]=(__bf16)(f0.y*qsc);
        q[2]=(__bf16)(f0.z*qsc); q[3]=(__bf16)(f0.w*qsc);
        q[4]=(__bf16)(f1.x*qsc); q[5]=(__bf16)(f1.y*qsc);
        q[6]=(__bf16)(f1.z*qsc); q[7]=(__bf16)(f1.w*qsc);
        qf[t] = q;
      }
    }

    f32x16 po0, po1;
    #pragma unroll
    for (int r = 0; r < 16; ++r) { po0[r] = 0.f; po1[r] = 0.f; }
    float m_run = -1e30f, l_run = 0.f;

    ldK(w);     // kt = w always exists in the 64-tile bh buffer
    ldV(w);

    for (int kt = w; kt < NT; kt += 4) {
      const bool more = (kt + 4 < NT);

      // S^T via mfma(K, Q): sa[r] = S[k = kt*32 + crow(r,h)][q = q0 + qc]
      f32x16 sa;
      #pragma unroll
      for (int r = 0; r < 16; ++r) sa[r] = 0.f;
      __builtin_amdgcn_s_setprio(1);
      #pragma unroll
      for (int t = 0; t < 4; ++t)
        sa = __builtin_amdgcn_mfma_f32_32x32x16_bf16(kfr[t], qf[t], sa, 0, 0, 0);
      __builtin_amdgcn_s_setprio(0);

      if (more) ldK(kt + 4);   // prefetch next K (lands under softmax+PV)

      if (kt == NT - 1) {      // causal mask: diag tile only
        #pragma unroll
        for (int r = 0; r < 16; ++r)
          if (((r & 3) + 8 * (r >> 2) + 4 * h) > qc) sa[r] = -1e30f;
      }

      // row max: in-lane tree + cross-half shfl_xor
      float rmax;
      {
        float a0 = fmaxf(fmaxf(sa[0], sa[1]),  fmaxf(sa[2], sa[3]));
        float a1 = fmaxf(fmaxf(sa[4], sa[5]),  fmaxf(sa[6], sa[7]));
        float a2 = fmaxf(fmaxf(sa[8], sa[9]),  fmaxf(sa[10], sa[11]));
        float a3 = fmaxf(fmaxf(sa[12], sa[13]), fmaxf(sa[14], sa[15]));
        rmax = fmaxf(fmaxf(a0, a1), fmaxf(a2, a3));
        rmax = fmaxf(rmax, __shfl_xor(rmax, 32));
      }

      // defer-max (T13)
      if (__any(rmax > m_run + 8.0f)) {
        float mn    = fmaxf(m_run, rmax);
        float alpha = exp2f(m_run - mn);
        m_run = mn;
        l_run *= alpha;
        #pragma unroll
        for (int r = 0; r < 16; ++r) {
          float ar = __shfl(alpha, (r & 3) + 8 * (r >> 2) + 4 * h);
          po0[r] *= ar;
          po1[r] *= ar;
        }
      }

      // P = exp2(S - m); in-lane sum tree + cross-half shfl_xor
      #pragma unroll
      for (int r = 0; r < 16; ++r) sa[r] = exp2f(sa[r] - m_run);
      {
        float s0 = (sa[0] + sa[1]) + (sa[2] + sa[3]);
        float s1 = (sa[4] + sa[5]) + (sa[6] + sa[7]);
        float s2 = (sa[8] + sa[9]) + (sa[10] + sa[11]);
        float s3 = (sa[12] + sa[13]) + (sa[14] + sa[15]);
        float rs = (s0 + s1) + (s2 + s3);
        l_run += rs + __shfl_xor(rs, 32);
      }

      // P -> bf16 PA fragments (r11-verified mapping, 4 shfl_xor)
      bf16x8 pa0, pa1;
      {
        unsigned k0 = pk2(sa[0], sa[1]),   k1 = pk2(sa[2], sa[3]);
        unsigned k2 = pk2(sa[4], sa[5]),   k3 = pk2(sa[6], sa[7]);
        unsigned k4 = pk2(sa[8], sa[9]),   k5 = pk2(sa[10], sa[11]);
        unsigned k6 = pk2(sa[12], sa[13]), k7 = pk2(sa[14], sa[15]);
        unsigned x02 = h ? k0 : k2, x13 = h ? k1 : k3;
        unsigned x46 = h ? k4 : k6, x57 = h ? k5 : k7;
        unsigned p02 = (unsigned)__shfl_xor((int)x02, 32);
        unsigned p13 = (unsigned)__shfl_xor((int)x13, 32);
        unsigned p46 = (unsigned)__shfl_xor((int)x46, 32);
        unsigned p57 = (unsigned)__shfl_xor((int)x57, 32);
        union { unsigned u[4]; bf16x8 v; } a, b;
        a.u[0] = h ? p02 : k0;  a.u[1] = h ? p13 : k1;
        a.u[2] = h ? k2 : p02;  a.u[3] = h ? k3 : p13;
        b.u[0] = h ? p46 : k4;  b.u[1] = h ? p57 : k5;
        b.u[2] = h ? k6 : p46;  b.u[3] = h ? k7 : p57;
        pa0 = a.v;
        pa1 = b.v;
      }

      // O += P V
      __builtin_amdgcn_s_setprio(1);
      po0 = __builtin_amdgcn_mfma_f32_32x32x16_bf16(pa0, vfr[0], po0, 0, 0, 0);
      po0 = __builtin_amdgcn_mfma_f32_32x32x16_bf16(pa1, vfr[1], po0, 0, 0, 0);
      po1 = __builtin_amdgcn_mfma_f32_32x32x16_bf16(pa0, vfr[2], po1, 0, 0, 0);
      po1 = __builtin_amdgcn_mfma_f32_32x32x16_bf16(pa1, vfr[3], po1, 0, 0, 0);
      __builtin_amdgcn_s_setprio(0);

      if (more) ldV(kt + 4);   // prefetch next V
    }

    // ---- write partials, 4-way flash-merge ----
    if (phase) __syncthreads();   // ensure phase-A merge readers done before overwrite
    #pragma unroll
    for (int r = 0; r < 16; ++r) {
      int crow = (r & 3) + 8 * (r >> 2) + 4 * h;
      o_sm[w][crow][qc]      = po0[r];
      o_sm[w][crow][qc + 32] = po1[r];
    }
    if (h == 0) { m_sm[w][qc] = m_run; l_sm[w][qc] = l_run; }
    __syncthreads();

    {
      const int q  = tid >> 3;          // 0..31
      const int d0 = (tid & 7) * 8;     // 0,8,..56
      float m0 = m_sm[0][q], m1 = m_sm[1][q];
      float m2 = m_sm[2][q], m3 = m_sm[3][q];
      float M  = fmaxf(fmaxf(m0, m1), fmaxf(m2, m3));
      float a0 = exp2f(m0 - M), a1 = exp2f(m1 - M);
      float a2 = exp2f(m2 - M), a3 = exp2f(m3 - M);
      float inv = 1.0f / (a0 * l_sm[0][q] + a1 * l_sm[1][q]
                        + a2 * l_sm[2][q] + a3 * l_sm[3][q]);
      float* og = Og + base + (long)(q0 + q) * D_DIM + d0;
      #pragma unroll
      for (int half = 0; half < 2; ++half) {
        float4 x0 = *reinterpret_cast<const float4*>(&o_sm[0][q][d0 + 4 * half]);
        float4 x1 = *reinterpret_cast<const float4*>(&o_sm[1][q][d0 + 4 * half]);
        float4 x2 = *reinterpret_cast<const float4*>(&o_sm[2][q][d0 + 4 * half]);
        float4 x3 = *reinterpret_cast<const float4*>(&o_sm[3][q][d0 + 4 * half]);
        float4 o;
        o.x = (a0 * x0.x + a1 * x1.x + a2 * x2.x + a3 * x3.x) * inv;
        o.y = (a0 * x0.y + a1 * x1.y + a2 * x2.y + a3 * x3.y) * inv;
        o.z = (a0 * x0.z + a1 * x1.z + a2 * x2.z + a3 * x3.z) * inv;
        o.w = (a0 * x0.w + a1 * x1.w + a2 * x2.w + a3 * x3.w) * inv;
        *reinterpret_cast<float4*>(og + 4 * half) = o;
      }
    }
  }
}

// ---------------- fallback (round-5 kernel) if ws too small ----------------
__global__ __launch_bounds__(256) void attn_fwd_fallback(
    const float* __restrict__ Vg, const float* __restrict__ Qg,
    const float* __restrict__ Kg, float* __restrict__ Og) {
  __shared__ __align__(16) unsigned char k_lds[64 * 128];
  __shared__ __align__(16) unsigned char vt_lds[64 * 128];
  __shared__ __align__(16) unsigned char p_lds[4][16 * 128];

  const int tid  = threadIdx.x;
  const int lane = tid & 63;
  const int w    = tid >> 6;
  const int lr   = lane & 15;
  const int lg   = lane >> 4;
  const int swz  = (lr & 7) << 4;

  const int lb = blockIdx.x;
  const int e  = lb & 7;
  const int s  = lb >> 3;
  const int bh = e + 8 * (s >> 5);
  const int qs = s & 31;
  const int qt = (qs & 1) ? (NQT - 1 - (qs >> 1)) : (qs >> 1);
  const long base = (long)bh * (S_LEN * D_DIM);
  const int q0 = qt * 64;

  bf16x8 qf[2];
  {
    const float qsc = 0.125f * 1.44269504f;
    const float* qp = Qg + base + (q0 + w * 16 + lr) * D_DIM + lg * 8;
    #pragma unroll
    for (int c = 0; c < 2; ++c) {
      float4 f0 = *reinterpret_cast<const float4*>(qp + c * 32);
      float4 f1 = *reinterpret_cast<const float4*>(qp + c * 32 + 4);
      bf16x8 t;
      t[0]=(__bf16)(f0.x*qsc); t[1]=(__bf16)(f0.y*qsc);
      t[2]=(__bf16)(f0.z*qsc); t[3]=(__bf16)(f0.w*qsc);
      t[4]=(__bf16)(f1.x*qsc); t[5]=(__bf16)(f1.y*qsc);
      t[6]=(__bf16)(f1.z*qsc); t[7]=(__bf16)(f1.w*qsc);
      qf[c] = t;
    }
  }
  bf16x8 onesf;
  #pragma unroll
  for (int j = 0; j < 8; ++j) onesf[j] = (lr == 0) ? (__bf16)1.0f : (__bf16)0.0f;

  f32x4 po[4], pl;
  float m_run = -1e30f;
  #pragma unroll
  for (int j = 0; j < 4; ++j) po[j] = (f32x4){0.f,0.f,0.f,0.f};
  pl = (f32x4){0.f,0.f,0.f,0.f};

  float4 kreg[4];
  float  vreg[16];
  const int d_ = lane;
  const int kb = w;

  auto load_regs = [&](int kt) {
    const float* kg = Kg + base + kt * (64 * D_DIM);
    #pragma unroll
    for (int i = 0; i < 4; ++i) {
      int idx = tid + 256 * i;
      int r = idx >> 4, f4 = idx & 15;
      kreg[i] = *reinterpret_cast<const float4*>(kg + r * 64 + f4 * 4);
    }
    const float* vg = Vg + base + kt * (64 * D_DIM);
    #pragma unroll
    for (int j = 0; j < 8; ++j) {
      vreg[j]     = vg[(kb * 8 + j) * 64 + d_];
      vreg[8 + j] = vg[((kb + 4) * 8 + j) * 64 + d_];
    }
  };
  auto write_buf = [&]() {
    #pragma unroll
    for (int i = 0; i < 4; ++i) {
      int idx = tid + 256 * i;
      int r = idx >> 4, f4 = idx & 15;
      bf16x4 t;
      t[0]=(__bf16)kreg[i].x; t[1]=(__bf16)kreg[i].y;
      t[2]=(__bf16)kreg[i].z; t[3]=(__bf16)kreg[i].w;
      int b = r * 128 + ((f4 * 8) ^ ((r & 7) << 4));
      *reinterpret_cast<bf16x4*>(&k_lds[b]) = t;
    }
    bf16x8 t0, t1;
    #pragma unroll
    for (int j = 0; j < 8; ++j) { t0[j] = (__bf16)vreg[j]; t1[j] = (__bf16)vreg[8+j]; }
    int b0 = d_ * 128 + ((kb * 16) ^ ((d_ & 7) << 4));
    int b1 = d_ * 128 + (((kb + 4) * 16) ^ ((d_ & 7) << 4));
    *reinterpret_cast<bf16x8*>(&vt_lds[b0]) = t0;
    *reinterpret_cast<bf16x8*>(&vt_lds[b1]) = t1;
  };

  load_regs(0);
  write_buf();
  __syncthreads();

  for (int kt = 0; kt <= qt; ++kt) {
    const bool last = (kt == qt);
    if (!last) load_regs(kt + 1);

    f32x4 sa[4];
    #pragma unroll
    for (int ct = 0; ct < 4; ++ct) sa[ct] = (f32x4){0.f,0.f,0.f,0.f};
    #pragma unroll
    for (int ct = 0; ct < 4; ++ct) {
      #pragma unroll
      for (int c = 0; c < 2; ++c) {
        int b = (ct * 16 + lr) * 128 + ((lg * 16 + c * 64) ^ swz);
        bf16x8 kf = *reinterpret_cast<const bf16x8*>(&k_lds[b]);
        sa[ct] = __builtin_amdgcn_mfma_f32_16x16x32_bf16(kf, qf[c], sa[ct], 0, 0, 0);
      }
    }
    if (last) {
      #pragma unroll
      for (int ct = 0; ct < 4; ++ct)
        #pragma unroll
        for (int j = 0; j < 4; ++j)
          if (ct * 16 + lg * 4 + j > w * 16 + lr) sa[ct][j] = -1e30f;
    }
    float rmax = sa[0][0];
    #pragma unroll
    for (int ct = 0; ct < 4; ++ct)
      #pragma unroll
      for (int j = 0; j < 4; ++j) rmax = fmaxf(rmax, sa[ct][j]);
    rmax = fmaxf(rmax, __shfl_xor(rmax, 16));
    rmax = fmaxf(rmax, __shfl_xor(rmax, 32));
    float mn    = fmaxf(m_run, rmax);
    float alpha = exp2f(m_run - mn);
    m_run = mn;
    #pragma unroll
    for (int ct = 0; ct < 4; ++ct) {
      bf16x4 t;
      #pragma unroll
      for (int j = 0; j < 4; ++j) t[j] = (__bf16)exp2f(sa[ct][j] - mn);
      int b = lr * 128 + ((ct * 32 + lg * 8) ^ swz);
      *reinterpret_cast<bf16x4*>(&p_lds[w][b]) = t;
    }
    float aj[4];
    #pragma unroll
    for (int j = 0; j < 4; ++j) aj[j] = __shfl(alpha, (lane & 48) | (lg * 4 + j));
    #pragma unroll
    for (int j = 0; j < 4; ++j) {
      pl[j] *= aj[j];
      #pragma unroll
      for (int dt = 0; dt < 4; ++dt) po[dt][j] *= aj[j];
    }
    #pragma unroll
    for (int c = 0; c < 2; ++c) {
      int ab = lr * 128 + ((lg * 16 + c * 64) ^ swz);
      bf16x8 pa = *reinterpret_cast<const bf16x8*>(&p_lds[w][ab]);
      pl = __builtin_amdgcn_mfma_f32_16x16x32_bf16(pa, onesf, pl, 0, 0, 0);
      #pragma unroll
      for (int dt = 0; dt < 4; ++dt) {
        int vb_ = (dt * 16 + lr) * 128 + ((lg * 16 + c * 64) ^ swz);
        bf16x8 vb = *reinterpret_cast<const bf16x8*>(&vt_lds[vb_]);
        po[dt] = __builtin_amdgcn_mfma_f32_16x16x32_bf16(pa, vb, po[dt], 0, 0, 0);
      }
    }
    if (!last) {
      __syncthreads();
      write_buf();
      __syncthreads();
    }
  }
  #pragma unroll
  for (int j = 0; j < 4; ++j) {
    float lv  = __shfl(pl[j], lane & 48);
    float inv = 1.0f / lv;
    int row = q0 + w * 16 + lg * 4 + j;
    #pragma unroll
    for (int dt = 0; dt < 4; ++dt)
      Og[base + row * D_DIM + dt * 16 + lr] = po[dt][j] * inv;
  }
}

extern "C" void kernel_launch(void* const* d_in, const int* in_sizes, int n_in,
                              void* d_out, int out_size, void* d_ws, size_t ws_size,
                              hipStream_t stream) {
  const float* V = (const float*)d_in[0];
  const float* Q = (const float*)d_in[1];
  const float* K = (const float*)d_in[2];
  float* O = (float*)d_out;
  const size_t need = (size_t)2 * 32 * 64 * 4096;  // Kb + Vt = 16 MB
  if (ws_size >= need) {
    unsigned char* Kb = (unsigned char*)d_ws;
    unsigned char* Vt = Kb + (size_t)32 * 64 * 4096;
    preprocess_kernel<<<dim3(2048), dim3(256), 0, stream>>>(K, V, Kb, Vt);
    attn_fwd_pair<<<dim3(1024), dim3(256), 0, stream>>>(Q, Kb, Vt, O);
  } else {
    attn_fwd_fallback<<<dim3(1024), dim3(256), 0, stream>>>(V, Q, K, O);
  }
}

// Round 14
// 58.046 us; speedup vs baseline: 1.3850x; 1.0665x over previous
//
#include <hip/hip_runtime.h>
#include <hip/hip_bf16.h>

typedef __bf16 bf16x8 __attribute__((ext_vector_type(8)));
typedef __bf16 bf16x4 __attribute__((ext_vector_type(4)));
typedef __bf16 bf16x2 __attribute__((ext_vector_type(2)));
typedef float f32x4 __attribute__((ext_vector_type(4)));
typedef float f32x16 __attribute__((ext_vector_type(16)));

#define S_LEN 2048
#define D_DIM 64
#define NQT   32

// pack two f32 -> u32 of 2 bf16 (compiler fuses to v_cvt_pk_bf16_f32)
static __device__ __forceinline__ unsigned pk2(float a, float b) {
  bf16x2 t; t[0] = (__bf16)a; t[1] = (__bf16)b;
  return __builtin_bit_cast(unsigned, t);
}

// ---------------- preprocess: 32x32-MFMA fragment images (r11-verified) ----------------
__global__ __launch_bounds__(256) void preprocess_kernel(
    const float* __restrict__ Kg, const float* __restrict__ Vg,
    unsigned char* __restrict__ Kb, unsigned char* __restrict__ Vt) {
  __shared__ float buf[2048];   // 8 KB: one 32x64 fp32 tile
  const int tid  = threadIdx.x;
  const int tile = blockIdx.x;          // bh*64 + kt
  const float* kg = Kg + (long)tile * 2048;
  const float* vg = Vg + (long)tile * 2048;
  unsigned char* kb = Kb + (long)tile * 4096;
  unsigned char* vt = Vt + (long)tile * 4096;

  const int l = tid & 63, f = tid >> 6, h = l >> 5;

  {
    const float* kr = kg + (l & 31) * 64 + f * 16 + h * 8;
    float4 a = *reinterpret_cast<const float4*>(kr);
    float4 b = *reinterpret_cast<const float4*>(kr + 4);
    bf16x8 t;
    t[0]=(__bf16)a.x; t[1]=(__bf16)a.y; t[2]=(__bf16)a.z; t[3]=(__bf16)a.w;
    t[4]=(__bf16)b.x; t[5]=(__bf16)b.y; t[6]=(__bf16)b.z; t[7]=(__bf16)b.w;
    *reinterpret_cast<bf16x8*>(kb + tid * 16) = t;
  }
  #pragma unroll
  for (int i = 0; i < 2; ++i) {
    int idx = tid + 256 * i;
    *reinterpret_cast<float4*>(buf + idx * 4) =
        *reinterpret_cast<const float4*>(vg + idx * 4);
  }
  __syncthreads();
  {
    int dt = f >> 1, ks = f & 1;
    int d  = dt * 32 + (l & 31);
    int k0 = ks * 16 + h * 8;
    bf16x8 t;
    #pragma unroll
    for (int j = 0; j < 8; ++j) t[j] = (__bf16)buf[(k0 + j) * 64 + d];
    *reinterpret_cast<bf16x8*>(vt + tid * 16) = t;
  }
}

// ---------------- main: 64 q-rows per wave, balanced pairs, split-K x4 ----------------
// Block = 256 threads = 4 waves; handles 64-row group pair (pi, 31-pi) in two
// phases (66 tiles total: perfectly balanced). Each wave holds TWO q-column
// blocks A (rows q0..q0+31) and B (q0+32..q0+63) that SHARE each K/V fragment
// load: 16 MFMAs per 8 KB (2x the arithmetic intensity of r13). Split-K x4
// (wave w: kt = w mod 4) with private (m,l,O) per sub-block; 4-way LDS
// flash-merge per sub-block. Per-tile math byte-identical to r13 (verified).
__global__ __launch_bounds__(256, 2) void attn_fwd_q64(
    const float* __restrict__ Qg, const unsigned char* __restrict__ Kb,
    const unsigned char* __restrict__ Vt, float* __restrict__ Og) {
  __shared__ float o_sm[4][32][68];   // 34816 B merge arena (reused A then B)
  __shared__ float m_sm[4][32];
  __shared__ float l_sm[4][32];

  const int tid  = threadIdx.x;
  const int lane = tid & 63;
  const int w    = tid >> 6;     // wave 0..3 (k-residue)
  const int qc   = lane & 31;
  const int h    = lane >> 5;

  // decode: XCD-clustered bh (4 bh per XCD); pair index pi (0..15)
  const int b  = blockIdx.x;            // 0..511
  const int e  = b & 7;
  const int s  = b >> 3;                // 0..63
  const int bh = e + 8 * (s >> 4);      // 4 bh per XCD
  const int pi = s & 15;
  const long base = (long)bh * (S_LEN * D_DIM);

  const unsigned char* kb_bh = Kb + (long)bh * 64 * 4096 + lane * 16;
  const unsigned char* vt_bh = Vt + (long)bh * 64 * 4096 + lane * 16;

  bf16x8 kfr[4], vfr[4];
  auto ldK = [&](int kt) {
    const unsigned char* p = kb_bh + (long)kt * 4096;
    #pragma unroll
    for (int t = 0; t < 4; ++t)
      kfr[t] = *reinterpret_cast<const bf16x8*>(p + t * 1024);
  };
  auto ldV = [&](int kt) {
    const unsigned char* p = vt_bh + (long)kt * 4096;
    #pragma unroll
    for (int t = 0; t < 4; ++t)
      vfr[t] = *reinterpret_cast<const bf16x8*>(p + t * 1024);
  };

  // softmax + PV for one q-sub-block (r13-verified math)
  auto process = [&](f32x16& sa, float& m_run, float& l_run,
                     f32x16& po0, f32x16& po1) {
    float rmax;
    {
      float a0 = fmaxf(fmaxf(sa[0], sa[1]),  fmaxf(sa[2], sa[3]));
      float a1 = fmaxf(fmaxf(sa[4], sa[5]),  fmaxf(sa[6], sa[7]));
      float a2 = fmaxf(fmaxf(sa[8], sa[9]),  fmaxf(sa[10], sa[11]));
      float a3 = fmaxf(fmaxf(sa[12], sa[13]), fmaxf(sa[14], sa[15]));
      rmax = fmaxf(fmaxf(a0, a1), fmaxf(a2, a3));
      rmax = fmaxf(rmax, __shfl_xor(rmax, 32));
    }
    if (__any(rmax > m_run + 8.0f)) {       // defer-max (T13)
      float mn    = fmaxf(m_run, rmax);
      float alpha = exp2f(m_run - mn);
      m_run = mn;
      l_run *= alpha;
      #pragma unroll
      for (int r = 0; r < 16; ++r) {
        float ar = __shfl(alpha, (r & 3) + 8 * (r >> 2) + 4 * h);
        po0[r] *= ar;
        po1[r] *= ar;
      }
    }
    #pragma unroll
    for (int r = 0; r < 16; ++r) sa[r] = exp2f(sa[r] - m_run);
    {
      float s0 = (sa[0] + sa[1]) + (sa[2] + sa[3]);
      float s1 = (sa[4] + sa[5]) + (sa[6] + sa[7]);
      float s2 = (sa[8] + sa[9]) + (sa[10] + sa[11]);
      float s3 = (sa[12] + sa[13]) + (sa[14] + sa[15]);
      float rs = (s0 + s1) + (s2 + s3);
      l_run += rs + __shfl_xor(rs, 32);
    }
    bf16x8 pa0, pa1;
    {
      unsigned k0 = pk2(sa[0], sa[1]),   k1 = pk2(sa[2], sa[3]);
      unsigned k2 = pk2(sa[4], sa[5]),   k3 = pk2(sa[6], sa[7]);
      unsigned k4 = pk2(sa[8], sa[9]),   k5 = pk2(sa[10], sa[11]);
      unsigned k6 = pk2(sa[12], sa[13]), k7 = pk2(sa[14], sa[15]);
      unsigned x02 = h ? k0 : k2, x13 = h ? k1 : k3;
      unsigned x46 = h ? k4 : k6, x57 = h ? k5 : k7;
      unsigned p02 = (unsigned)__shfl_xor((int)x02, 32);
      unsigned p13 = (unsigned)__shfl_xor((int)x13, 32);
      unsigned p46 = (unsigned)__shfl_xor((int)x46, 32);
      unsigned p57 = (unsigned)__shfl_xor((int)x57, 32);
      union { unsigned u[4]; bf16x8 v; } a2, b2;
      a2.u[0] = h ? p02 : k0;  a2.u[1] = h ? p13 : k1;
      a2.u[2] = h ? k2 : p02;  a2.u[3] = h ? k3 : p13;
      b2.u[0] = h ? p46 : k4;  b2.u[1] = h ? p57 : k5;
      b2.u[2] = h ? k6 : p46;  b2.u[3] = h ? k7 : p57;
      pa0 = a2.v;
      pa1 = b2.v;
    }
    __builtin_amdgcn_s_setprio(1);
    po0 = __builtin_amdgcn_mfma_f32_32x32x16_bf16(pa0, vfr[0], po0, 0, 0, 0);
    po0 = __builtin_amdgcn_mfma_f32_32x32x16_bf16(pa1, vfr[1], po0, 0, 0, 0);
    po1 = __builtin_amdgcn_mfma_f32_32x32x16_bf16(pa0, vfr[2], po1, 0, 0, 0);
    po1 = __builtin_amdgcn_mfma_f32_32x32x16_bf16(pa1, vfr[3], po1, 0, 0, 0);
    __builtin_amdgcn_s_setprio(0);
  };

  // merge one 32-row sub-block: write partials -> sync -> 4-way flash-merge
  auto submerge = [&](const f32x16& po0, const f32x16& po1,
                      float m_run, float l_run, int qbase) {
    #pragma unroll
    for (int r = 0; r < 16; ++r) {
      int crow = (r & 3) + 8 * (r >> 2) + 4 * h;
      o_sm[w][crow][qc]      = po0[r];
      o_sm[w][crow][qc + 32] = po1[r];
    }
    if (h == 0) { m_sm[w][qc] = m_run; l_sm[w][qc] = l_run; }
    __syncthreads();
    {
      const int q  = tid >> 3;          // 0..31
      const int d0 = (tid & 7) * 8;     // 0,8,..56
      float m0 = m_sm[0][q], m1 = m_sm[1][q];
      float m2 = m_sm[2][q], m3 = m_sm[3][q];
      float M  = fmaxf(fmaxf(m0, m1), fmaxf(m2, m3));
      float a0 = exp2f(m0 - M), a1 = exp2f(m1 - M);
      float a2 = exp2f(m2 - M), a3 = exp2f(m3 - M);
      float inv = 1.0f / (a0 * l_sm[0][q] + a1 * l_sm[1][q]
                        + a2 * l_sm[2][q] + a3 * l_sm[3][q]);
      float* og = Og + base + (long)(qbase + q) * D_DIM + d0;
      #pragma unroll
      for (int half = 0; half < 2; ++half) {
        float4 x0 = *reinterpret_cast<const float4*>(&o_sm[0][q][d0 + 4 * half]);
        float4 x1 = *reinterpret_cast<const float4*>(&o_sm[1][q][d0 + 4 * half]);
        float4 x2 = *reinterpret_cast<const float4*>(&o_sm[2][q][d0 + 4 * half]);
        float4 x3 = *reinterpret_cast<const float4*>(&o_sm[3][q][d0 + 4 * half]);
        float4 o;
        o.x = (a0 * x0.x + a1 * x1.x + a2 * x2.x + a3 * x3.x) * inv;
        o.y = (a0 * x0.y + a1 * x1.y + a2 * x2.y + a3 * x3.y) * inv;
        o.z = (a0 * x0.z + a1 * x1.z + a2 * x2.z + a3 * x3.z) * inv;
        o.w = (a0 * x0.w + a1 * x1.w + a2 * x2.w + a3 * x3.w) * inv;
        *reinterpret_cast<float4*>(og + 4 * half) = o;
      }
    }
  };

  for (int phase = 0; phase < 2; ++phase) {
    const int g  = phase ? pi : (31 - pi);   // 64-row group
    const int q0 = g * 64;
    const int NT = 2 * g + 2;                // 32-wide k-tiles

    // Q fragments for sub-blocks A and B, prescaled by 1/8 * log2(e)
    bf16x8 qfA[4], qfB[4];
    {
      const float qsc = 0.125f * 1.44269504f;
      const float* qpA = Qg + base + (long)(q0 + qc) * D_DIM + h * 8;
      const float* qpB = qpA + 32 * D_DIM;
      #pragma unroll
      for (int t = 0; t < 4; ++t) {
        float4 f0 = *reinterpret_cast<const float4*>(qpA + t * 16);
        float4 f1 = *reinterpret_cast<const float4*>(qpA + t * 16 + 4);
        bf16x8 q;
        q[0]=(__bf16)(f0.x*qsc); q[1]=(__bf16)(f0.y*qsc);
        q[2]=(__bf16)(f0.z*qsc); q[3]=(__bf16)(f0.w*qsc);
        q[4]=(__bf16)(f1.x*qsc); q[5]=(__bf16)(f1.y*qsc);
        q[6]=(__bf16)(f1.z*qsc); q[7]=(__bf16)(f1.w*qsc);
        qfA[t] = q;
        f0 = *reinterpret_cast<const float4*>(qpB + t * 16);
        f1 = *reinterpret_cast<const float4*>(qpB + t * 16 + 4);
        q[0]=(__bf16)(f0.x*qsc); q[1]=(__bf16)(f0.y*qsc);
        q[2]=(__bf16)(f0.z*qsc); q[3]=(__bf16)(f0.w*qsc);
        q[4]=(__bf16)(f1.x*qsc); q[5]=(__bf16)(f1.y*qsc);
        q[6]=(__bf16)(f1.z*qsc); q[7]=(__bf16)(f1.w*qsc);
        qfB[t] = q;
      }
    }

    f32x16 poA0, poA1, poB0, poB1;
    #pragma unroll
    for (int r = 0; r < 16; ++r) { poA0[r]=0.f; poA1[r]=0.f; poB0[r]=0.f; poB1[r]=0.f; }
    float mA = -1e30f, lA = 0.f, mB = -1e30f, lB = 0.f;

    ldK(w);   // kt = w always exists in the 64-tile bh buffer
    ldV(w);

    for (int kt = w; kt < NT; kt += 4) {
      const bool more = (kt + 4 < NT);
      const bool doA  = (kt != NT - 1);   // tile NT-1 is fully past A's rows

      // S^T via mfma(K, Q) for both sub-blocks (shared kfr)
      f32x16 saA, saB;
      __builtin_amdgcn_s_setprio(1);
      if (doA) {
        #pragma unroll
        for (int r = 0; r < 16; ++r) saA[r] = 0.f;
        #pragma unroll
        for (int t = 0; t < 4; ++t)
          saA = __builtin_amdgcn_mfma_f32_32x32x16_bf16(kfr[t], qfA[t], saA, 0, 0, 0);
      }
      #pragma unroll
      for (int r = 0; r < 16; ++r) saB[r] = 0.f;
      #pragma unroll
      for (int t = 0; t < 4; ++t)
        saB = __builtin_amdgcn_mfma_f32_32x32x16_bf16(kfr[t], qfB[t], saB, 0, 0, 0);
      __builtin_amdgcn_s_setprio(0);

      if (more) ldK(kt + 4);   // prefetch next K (kfr free after both QKs)

      // causal diag masks: A at kt==NT-2, B at kt==NT-1; both reduce to crow>qc
      if (kt == NT - 2) {
        #pragma unroll
        for (int r = 0; r < 16; ++r)
          if (((r & 3) + 8 * (r >> 2) + 4 * h) > qc) saA[r] = -1e30f;
      }
      if (kt == NT - 1) {
        #pragma unroll
        for (int r = 0; r < 16; ++r)
          if (((r & 3) + 8 * (r >> 2) + 4 * h) > qc) saB[r] = -1e30f;
      }

      if (doA) process(saA, mA, lA, poA0, poA1);
      process(saB, mB, lB, poB0, poB1);

      if (more) ldV(kt + 4);   // prefetch next V
    }

    if (phase) __syncthreads();          // prior merge readers done
    submerge(poA0, poA1, mA, lA, q0);
    __syncthreads();                     // merge-A reads done before B writes
    submerge(poB0, poB1, mB, lB, q0 + 32);
  }
}

// ---------------- fallback (round-5 kernel) if ws too small ----------------
__global__ __launch_bounds__(256) void attn_fwd_fallback(
    const float* __restrict__ Vg, const float* __restrict__ Qg,
    const float* __restrict__ Kg, float* __restrict__ Og) {
  __shared__ __align__(16) unsigned char k_lds[64 * 128];
  __shared__ __align__(16) unsigned char vt_lds[64 * 128];
  __shared__ __align__(16) unsigned char p_lds[4][16 * 128];

  const int tid  = threadIdx.x;
  const int lane = tid & 63;
  const int w    = tid >> 6;
  const int lr   = lane & 15;
  const int lg   = lane >> 4;
  const int swz  = (lr & 7) << 4;

  const int lb = blockIdx.x;
  const int e  = lb & 7;
  const int s  = lb >> 3;
  const int bh = e + 8 * (s >> 5);
  const int qs = s & 31;
  const int qt = (qs & 1) ? (NQT - 1 - (qs >> 1)) : (qs >> 1);
  const long base = (long)bh * (S_LEN * D_DIM);
  const int q0 = qt * 64;

  bf16x8 qf[2];
  {
    const float qsc = 0.125f * 1.44269504f;
    const float* qp = Qg + base + (q0 + w * 16 + lr) * D_DIM + lg * 8;
    #pragma unroll
    for (int c = 0; c < 2; ++c) {
      float4 f0 = *reinterpret_cast<const float4*>(qp + c * 32);
      float4 f1 = *reinterpret_cast<const float4*>(qp + c * 32 + 4);
      bf16x8 t;
      t[0]=(__bf16)(f0.x*qsc); t[1]=(__bf16)(f0.y*qsc);
      t[2]=(__bf16)(f0.z*qsc); t[3]=(__bf16)(f0.w*qsc);
      t[4]=(__bf16)(f1.x*qsc); t[5]=(__bf16)(f1.y*qsc);
      t[6]=(__bf16)(f1.z*qsc); t[7]=(__bf16)(f1.w*qsc);
      qf[c] = t;
    }
  }
  bf16x8 onesf;
  #pragma unroll
  for (int j = 0; j < 8; ++j) onesf[j] = (lr == 0) ? (__bf16)1.0f : (__bf16)0.0f;

  f32x4 po[4], pl;
  float m_run = -1e30f;
  #pragma unroll
  for (int j = 0; j < 4; ++j) po[j] = (f32x4){0.f,0.f,0.f,0.f};
  pl = (f32x4){0.f,0.f,0.f,0.f};

  float4 kreg[4];
  float  vreg[16];
  const int d_ = lane;
  const int kb = w;

  auto load_regs = [&](int kt) {
    const float* kg = Kg + base + kt * (64 * D_DIM);
    #pragma unroll
    for (int i = 0; i < 4; ++i) {
      int idx = tid + 256 * i;
      int r = idx >> 4, f4 = idx & 15;
      kreg[i] = *reinterpret_cast<const float4*>(kg + r * 64 + f4 * 4);
    }
    const float* vg = Vg + base + kt * (64 * D_DIM);
    #pragma unroll
    for (int j = 0; j < 8; ++j) {
      vreg[j]     = vg[(kb * 8 + j) * 64 + d_];
      vreg[8 + j] = vg[((kb + 4) * 8 + j) * 64 + d_];
    }
  };
  auto write_buf = [&]() {
    #pragma unroll
    for (int i = 0; i < 4; ++i) {
      int idx = tid + 256 * i;
      int r = idx >> 4, f4 = idx & 15;
      bf16x4 t;
      t[0]=(__bf16)kreg[i].x; t[1]=(__bf16)kreg[i].y;
      t[2]=(__bf16)kreg[i].z; t[3]=(__bf16)kreg[i].w;
      int b = r * 128 + ((f4 * 8) ^ ((r & 7) << 4));
      *reinterpret_cast<bf16x4*>(&k_lds[b]) = t;
    }
    bf16x8 t0, t1;
    #pragma unroll
    for (int j = 0; j < 8; ++j) { t0[j] = (__bf16)vreg[j]; t1[j] = (__bf16)vreg[8+j]; }
    int b0 = d_ * 128 + ((kb * 16) ^ ((d_ & 7) << 4));
    int b1 = d_ * 128 + (((kb + 4) * 16) ^ ((d_ & 7) << 4));
    *reinterpret_cast<bf16x8*>(&vt_lds[b0]) = t0;
    *reinterpret_cast<bf16x8*>(&vt_lds[b1]) = t1;
  };

  load_regs(0);
  write_buf();
  __syncthreads();

  for (int kt = 0; kt <= qt; ++kt) {
    const bool last = (kt == qt);
    if (!last) load_regs(kt + 1);

    f32x4 sa[4];
    #pragma unroll
    for (int ct = 0; ct < 4; ++ct) sa[ct] = (f32x4){0.f,0.f,0.f,0.f};
    #pragma unroll
    for (int ct = 0; ct < 4; ++ct) {
      #pragma unroll
      for (int c = 0; c < 2; ++c) {
        int b = (ct * 16 + lr) * 128 + ((lg * 16 + c * 64) ^ swz);
        bf16x8 kf = *reinterpret_cast<const bf16x8*>(&k_lds[b]);
        sa[ct] = __builtin_amdgcn_mfma_f32_16x16x32_bf16(kf, qf[c], sa[ct], 0, 0, 0);
      }
    }
    if (last) {
      #pragma unroll
      for (int ct = 0; ct < 4; ++ct)
        #pragma unroll
        for (int j = 0; j < 4; ++j)
          if (ct * 16 + lg * 4 + j > w * 16 + lr) sa[ct][j] = -1e30f;
    }
    float rmax = sa[0][0];
    #pragma unroll
    for (int ct = 0; ct < 4; ++ct)
      #pragma unroll
      for (int j = 0; j < 4; ++j) rmax = fmaxf(rmax, sa[ct][j]);
    rmax = fmaxf(rmax, __shfl_xor(rmax, 16));
    rmax = fmaxf(rmax, __shfl_xor(rmax, 32));
    float mn    = fmaxf(m_run, rmax);
    float alpha = exp2f(m_run - mn);
    m_run = mn;
    #pragma unroll
    for (int ct = 0; ct < 4; ++ct) {
      bf16x4 t;
      #pragma unroll
      for (int j = 0; j < 4; ++j) t[j] = (__bf16)exp2f(sa[ct][j] - mn);
      int b = lr * 128 + ((ct * 32 + lg * 8) ^ swz);
      *reinterpret_cast<bf16x4*>(&p_lds[w][b]) = t;
    }
    float aj[4];
    #pragma unroll
    for (int j = 0; j < 4; ++j) aj[j] = __shfl(alpha, (lane & 48) | (lg * 4 + j));
    #pragma unroll
    for (int j = 0; j < 4; ++j) {
      pl[j] *= aj[j];
      #pragma unroll
      for (int dt = 0; dt < 4; ++dt) po[dt][j] *= aj[j];
    }
    #pragma unroll
    for (int c = 0; c < 2; ++c) {
      int ab = lr * 128 + ((lg * 16 + c * 64) ^ swz);
      bf16x8 pa = *reinterpret_cast<const bf16x8*>(&p_lds[w][ab]);
      pl = __builtin_amdgcn_mfma_f32_16x16x32_bf16(pa, onesf, pl, 0, 0, 0);
      #pragma unroll
      for (int dt = 0; dt < 4; ++dt) {
        int vb_ = (dt * 16 + lr) * 128 + ((lg * 16 + c * 64) ^ swz);
        bf16x8 vb = *reinterpret_cast<const bf16x8*>(&vt_lds[vb_]);
        po[dt] = __builtin_amdgcn_mfma_f32_16x16x32_bf16(pa, vb, po[dt], 0, 0, 0);
      }
    }
    if (!last) {
      __syncthreads();
      write_buf();
      __syncthreads();
    }
  }
  #pragma unroll
  for (int j = 0; j < 4; ++j) {
    float lv  = __shfl(pl[j], lane & 48);
    float inv = 1.0f / lv;
    int row = q0 + w * 16 + lg * 4 + j;
    #pragma unroll
    for (int dt = 0; dt < 4; ++dt)
      Og[base + row * D_DIM + dt * 16 + lr] = po[dt][j] * inv;
  }
}

extern "C" void kernel_launch(void* const* d_in, const int* in_sizes, int n_in,
                              void* d_out, int out_size, void* d_ws, size_t ws_size,
                              hipStream_t stream) {
  const float* V = (const float*)d_in[0];
  const float* Q = (const float*)d_in[1];
  const float* K = (const float*)d_in[2];
  float* O = (float*)d_out;
  const size_t need = (size_t)2 * 32 * 64 * 4096;  // Kb + Vt = 16 MB
  if (ws_size >= need) {
    unsigned char* Kb = (unsigned char*)d_ws;
    unsigned char* Vt = Kb + (size_t)32 * 64 * 4096;
    preprocess_kernel<<<dim3(2048), dim3(256), 0, stream>>>(K, V, Kb, Vt);
    attn_fwd_q64<<<dim3(512), dim3(256), 0, stream>>>(Q, Kb, Vt, O);
  } else {
    attn_fwd_fallback<<<dim3(1024), dim3(256), 0, stream>>>(V, Q, K, O);
  }
}